// Round 1
// baseline (650.549 us; speedup 1.0000x reference)
//
#include <hip/hip_runtime.h>

#define N_NODES  50000
#define N_EDGES  800000
#define HID      128
#define OUT_C    16
#define N_GRAPHS 128

// ---------------- degree / normalization ----------------
__global__ void deg_count_kernel(const int* __restrict__ dst, int* __restrict__ deg) {
  int e = blockIdx.x * blockDim.x + threadIdx.x;
  if (e < N_EDGES) atomicAdd(&deg[dst[e]], 1);
}

__global__ void dis_kernel(const int* __restrict__ deg, float* __restrict__ dis) {
  int i = blockIdx.x * blockDim.x + threadIdx.x;
  if (i < N_NODES) dis[i] = rsqrtf((float)deg[i] + 1.0f);  // +1 = self-loop
}

// ---------------- exclusive scan (3 kernels) ----------------
__global__ void scan1_kernel(const int* __restrict__ deg, int* __restrict__ off,
                             int* __restrict__ bsum) {
  __shared__ int s[256];
  int i = blockIdx.x * 256 + threadIdx.x;
  int v = (i < N_NODES) ? deg[i] : 0;
  s[threadIdx.x] = v;
  __syncthreads();
  for (int d = 1; d < 256; d <<= 1) {
    int t = (threadIdx.x >= d) ? s[threadIdx.x - d] : 0;
    __syncthreads();
    s[threadIdx.x] += t;
    __syncthreads();
  }
  if (i < N_NODES) off[i] = s[threadIdx.x] - v;  // exclusive within block
  if (threadIdx.x == 255) bsum[blockIdx.x] = s[255];
}

__global__ void scan2_kernel(int* __restrict__ bsum, int nb) {
  __shared__ int s[256];
  int v = (threadIdx.x < nb) ? bsum[threadIdx.x] : 0;
  s[threadIdx.x] = v;
  __syncthreads();
  for (int d = 1; d < 256; d <<= 1) {
    int t = (threadIdx.x >= d) ? s[threadIdx.x - d] : 0;
    __syncthreads();
    s[threadIdx.x] += t;
    __syncthreads();
  }
  if (threadIdx.x < nb) bsum[threadIdx.x] = s[threadIdx.x] - v;  // exclusive
}

__global__ void scan3_kernel(int* __restrict__ off, const int* __restrict__ bsum) {
  int i = blockIdx.x * 256 + threadIdx.x;
  if (i < N_NODES) off[i] += bsum[blockIdx.x];
}

// ---------------- CSR fill ----------------
__global__ void fill_kernel(const int* __restrict__ src, const int* __restrict__ dst,
                            const int* __restrict__ off, int* __restrict__ cursor,
                            int* __restrict__ csr) {
  int e = blockIdx.x * blockDim.x + threadIdx.x;
  if (e < N_EDGES) {
    int d = dst[e];
    int p = atomicAdd(&cursor[d], 1);
    csr[off[d] + p] = src[e];
  }
}

// ---------------- dense GEMM: T[n,:] = H[n,:] @ W (128x128) ----------------
// 64 nodes/block; thread (cg = tid&31 -> 4 channels, ng = tid>>5 -> 8 nodes stride 8)
#define GN 64
#define KC 32
__global__ __launch_bounds__(256) void gemm128_kernel(
    const float* __restrict__ H, const float* __restrict__ W,
    float* __restrict__ T, int n_nodes) {
  __shared__ float sW[KC][HID];   // 16 KB
  __shared__ float sH[GN][KC];    // 8 KB
  const int tid = threadIdx.x;
  const int cg = tid & 31;
  const int ng = tid >> 5;
  const int base = blockIdx.x * GN;

  float4 acc[8];
#pragma unroll
  for (int i = 0; i < 8; ++i) acc[i] = make_float4(0.f, 0.f, 0.f, 0.f);

  for (int kc = 0; kc < HID; kc += KC) {
    __syncthreads();
#pragma unroll
    for (int i = 0; i < 4; ++i) {  // 1024 float4 of W-chunk
      int idx = tid + i * 256;
      ((float4*)sW)[idx] = ((const float4*)(W + (size_t)kc * HID))[idx];
    }
#pragma unroll
    for (int i = 0; i < 2; ++i) {  // 512 float4 of H-chunk
      int idx = tid + i * 256;
      int n = idx >> 3, kq = idx & 7;
      int node = base + n;
      float4 v = make_float4(0.f, 0.f, 0.f, 0.f);
      if (node < n_nodes) v = ((const float4*)(H + (size_t)node * HID + kc))[kq];
      ((float4*)sH)[idx] = v;
    }
    __syncthreads();
#pragma unroll
    for (int k = 0; k < KC; ++k) {
      float4 w = *(const float4*)&sW[k][cg * 4];
#pragma unroll
      for (int i = 0; i < 8; ++i) {
        float h = sH[ng + i * 8][k];
        acc[i].x += w.x * h; acc[i].y += w.y * h;
        acc[i].z += w.z * h; acc[i].w += w.w * h;
      }
    }
  }
#pragma unroll
  for (int i = 0; i < 8; ++i) {
    int node = base + ng + i * 8;
    if (node < n_nodes) ((float4*)(T + (size_t)node * HID))[cg] = acc[i];
  }
}

// ---------------- normalized aggregation + bias + relu ----------------
// one wave per destination node; lane owns 2 channels (float2)
__global__ __launch_bounds__(256) void aggregate_kernel(
    const float* __restrict__ T, const int* __restrict__ csr,
    const int* __restrict__ off, const int* __restrict__ deg,
    const float* __restrict__ dis, const float* __restrict__ bias,
    float* __restrict__ Hout) {
  int node = (blockIdx.x * blockDim.x + threadIdx.x) >> 6;
  int lane = threadIdx.x & 63;
  if (node >= N_NODES) return;
  float dd = dis[node];
  float2 b = ((const float2*)bias)[lane];
  float2 sv = ((const float2*)(T + (size_t)node * HID))[lane];
  float wself = dd * dd;
  float2 acc;
  acc.x = sv.x * wself;
  acc.y = sv.y * wself;
  int s0 = off[node], cnt = deg[node];
  for (int j = 0; j < cnt; ++j) {
    int s = csr[s0 + j];
    float w = dis[s] * dd;
    float2 hv = ((const float2*)(T + (size_t)s * HID))[lane];
    acc.x += hv.x * w;
    acc.y += hv.y * w;
  }
  acc.x = fmaxf(acc.x + b.x, 0.f);
  acc.y = fmaxf(acc.y + b.y, 0.f);
  ((float2*)(Hout + (size_t)node * HID))[lane] = acc;
}

// ---------------- pooling ----------------
__global__ void count_kernel(const int* __restrict__ batch, float* __restrict__ cnt) {
  int i = blockIdx.x * blockDim.x + threadIdx.x;
  if (i < N_NODES) atomicAdd(&cnt[batch[i]], 1.0f);
}

__global__ __launch_bounds__(256) void pool_kernel(
    const float* __restrict__ H, const int* __restrict__ batch,
    float* __restrict__ pooled) {
  int node = (blockIdx.x * blockDim.x + threadIdx.x) >> 6;
  int lane = threadIdx.x & 63;
  if (node >= N_NODES) return;
  int g = batch[node];
  float2 hv = ((const float2*)(H + (size_t)node * HID))[lane];
  atomicAdd(&pooled[g * HID + lane * 2], hv.x);
  atomicAdd(&pooled[g * HID + lane * 2 + 1], hv.y);
}

// ---------------- FC head + log_softmax (1 wave / graph) ----------------
__global__ __launch_bounds__(64) void head_kernel(
    const float* __restrict__ pooled, const float* __restrict__ cnt,
    const float* __restrict__ Wfc, const float* __restrict__ bfc,
    float* __restrict__ out) {
  int g = blockIdx.x;
  int lane = threadIdx.x;
  int o = lane & 15;
  float inv = 1.0f / fmaxf(cnt[g], 1.0f);
  float logit = bfc[o];
  for (int k = 0; k < HID; ++k)
    logit += (pooled[g * HID + k] * inv) * Wfc[k * OUT_C + o];
  float m = logit;
#pragma unroll
  for (int d = 8; d >= 1; d >>= 1) m = fmaxf(m, __shfl_xor(m, d, 16));
  float e = __expf(logit - m);
  float s = e;
#pragma unroll
  for (int d = 8; d >= 1; d >>= 1) s += __shfl_xor(s, d, 16);
  float r = logit - m - __logf(s);
  if (lane < 16) out[g * OUT_C + o] = r;
}

extern "C" void kernel_launch(void* const* d_in, const int* in_sizes, int n_in,
                              void* d_out, int out_size, void* d_ws, size_t ws_size,
                              hipStream_t stream) {
  const float* x    = (const float*)d_in[0];
  const int*   ei   = (const int*)d_in[1];
  const int*   batch= (const int*)d_in[2];
  const float* W1   = (const float*)d_in[3];
  const float* b1   = (const float*)d_in[4];
  const float* W2   = (const float*)d_in[5];
  const float* b2   = (const float*)d_in[6];
  const float* Wfc  = (const float*)d_in[7];
  const float* bfc  = (const float*)d_in[8];
  float* out = (float*)d_out;
  const int* src = ei;              // edge_index[0]
  const int* dst = ei + N_EDGES;    // edge_index[1]

  char* p = (char*)d_ws;
  auto alloc = [&](size_t bytes) { char* r = p; p += (bytes + 255) & ~255ull; return r; };
  int*   degI   = (int*)alloc((size_t)N_NODES * 4);
  float* dis    = (float*)alloc((size_t)N_NODES * 4);
  int*   off    = (int*)alloc((size_t)N_NODES * 4);
  int*   cursor = (int*)alloc((size_t)N_NODES * 4);
  int*   bsum   = (int*)alloc(256 * 4);
  float* cnt    = (float*)alloc(N_GRAPHS * 4);
  float* pooled = (float*)alloc((size_t)N_GRAPHS * HID * 4);
  int*   csr    = (int*)alloc((size_t)N_EDGES * 4);
  float* T      = (float*)alloc((size_t)N_NODES * HID * 4);
  float* H      = (float*)alloc((size_t)N_NODES * HID * 4);

  hipMemsetAsync(degI,   0, (size_t)N_NODES * 4, stream);
  hipMemsetAsync(cursor, 0, (size_t)N_NODES * 4, stream);
  hipMemsetAsync(cnt,    0, N_GRAPHS * 4, stream);
  hipMemsetAsync(pooled, 0, (size_t)N_GRAPHS * HID * 4, stream);

  int nbN = (N_NODES + 255) / 256;
  int nbE = (N_EDGES + 255) / 256;

  deg_count_kernel<<<nbE, 256, 0, stream>>>(dst, degI);
  dis_kernel<<<nbN, 256, 0, stream>>>(degI, dis);
  scan1_kernel<<<nbN, 256, 0, stream>>>(degI, off, bsum);
  scan2_kernel<<<1, 256, 0, stream>>>(bsum, nbN);
  scan3_kernel<<<nbN, 256, 0, stream>>>(off, bsum);
  fill_kernel<<<nbE, 256, 0, stream>>>(src, dst, off, cursor, csr);

  int gemm_blocks = (N_NODES + GN - 1) / GN;
  int agg_blocks  = (N_NODES * 64 + 255) / 256;

  gemm128_kernel<<<gemm_blocks, 256, 0, stream>>>(x, W1, T, N_NODES);
  aggregate_kernel<<<agg_blocks, 256, 0, stream>>>(T, csr, off, degI, dis, b1, H);
  gemm128_kernel<<<gemm_blocks, 256, 0, stream>>>(H, W2, T, N_NODES);
  aggregate_kernel<<<agg_blocks, 256, 0, stream>>>(T, csr, off, degI, dis, b2, H);

  count_kernel<<<nbN, 256, 0, stream>>>(batch, cnt);
  pool_kernel<<<agg_blocks, 256, 0, stream>>>(H, batch, pooled);
  head_kernel<<<N_GRAPHS, 64, 0, stream>>>(pooled, cnt, Wfc, bfc, out);
}

// Round 2
// 391.486 us; speedup vs baseline: 1.6617x; 1.6617x over previous
//
#include <hip/hip_runtime.h>

#define N_NODES  50000
#define N_EDGES  800000
#define HID      128
#define OUT_C    16
#define N_GRAPHS 128

// ---------------- degree ----------------
__global__ void deg_count_kernel(const int* __restrict__ dst, int* __restrict__ deg) {
  int e = blockIdx.x * blockDim.x + threadIdx.x;
  if (e < N_EDGES) atomicAdd(&deg[dst[e]], 1);
}

// ---------------- exclusive scan (3 kernels) ----------------
__global__ void scan1_kernel(const int* __restrict__ deg, int* __restrict__ off,
                             int* __restrict__ bsum) {
  __shared__ int s[256];
  int i = blockIdx.x * 256 + threadIdx.x;
  int v = (i < N_NODES) ? deg[i] : 0;
  s[threadIdx.x] = v;
  __syncthreads();
  for (int d = 1; d < 256; d <<= 1) {
    int t = (threadIdx.x >= d) ? s[threadIdx.x - d] : 0;
    __syncthreads();
    s[threadIdx.x] += t;
    __syncthreads();
  }
  if (i < N_NODES) off[i] = s[threadIdx.x] - v;  // exclusive within block
  if (threadIdx.x == 255) bsum[blockIdx.x] = s[255];
}

// scan2 over block sums + (fused) graph-boundary binary search on sorted batch
__global__ void scan2_bounds_kernel(int* __restrict__ bsum, int nb,
                                    const int* __restrict__ batch,
                                    int* __restrict__ start) {
  __shared__ int s[256];
  int v = (threadIdx.x < nb) ? bsum[threadIdx.x] : 0;
  s[threadIdx.x] = v;
  __syncthreads();
  for (int d = 1; d < 256; d <<= 1) {
    int t = (threadIdx.x >= d) ? s[threadIdx.x - d] : 0;
    __syncthreads();
    s[threadIdx.x] += t;
    __syncthreads();
  }
  if (threadIdx.x < nb) bsum[threadIdx.x] = s[threadIdx.x] - v;  // exclusive
  // graph segment boundaries: start[g] = lower_bound(batch, g), start[128] = N
  int t = threadIdx.x;
  if (t <= N_GRAPHS) {
    int lo = 0, hi = N_NODES;
    while (lo < hi) {
      int mid = (lo + hi) >> 1;
      if (batch[mid] < t) lo = mid + 1; else hi = mid;
    }
    start[t] = lo;
  }
}

// scan3 + (fused) deg_inv_sqrt
__global__ void scan3_dis_kernel(int* __restrict__ off, const int* __restrict__ bsum,
                                 const int* __restrict__ deg, float* __restrict__ dis) {
  int i = blockIdx.x * 256 + threadIdx.x;
  if (i < N_NODES) {
    off[i] += bsum[blockIdx.x];
    dis[i] = rsqrtf((float)deg[i] + 1.0f);  // +1 = self-loop
  }
}

// ---------------- CSR fill ----------------
__global__ void fill_kernel(const int* __restrict__ src, const int* __restrict__ dst,
                            const int* __restrict__ off, int* __restrict__ cursor,
                            int* __restrict__ csr) {
  int e = blockIdx.x * blockDim.x + threadIdx.x;
  if (e < N_EDGES) {
    int d = dst[e];
    int p = atomicAdd(&cursor[d], 1);
    csr[off[d] + p] = src[e];
  }
}

// ---------------- dense GEMM: T[n,:] = H[n,:] @ W (128x128) ----------------
#define GN 64
#define KC 32
__global__ __launch_bounds__(256) void gemm128_kernel(
    const float* __restrict__ H, const float* __restrict__ W,
    float* __restrict__ T, int n_nodes) {
  __shared__ float sW[KC][HID];   // 16 KB
  __shared__ float sH[GN][KC];    // 8 KB
  const int tid = threadIdx.x;
  const int cg = tid & 31;
  const int ng = tid >> 5;
  const int base = blockIdx.x * GN;

  float4 acc[8];
#pragma unroll
  for (int i = 0; i < 8; ++i) acc[i] = make_float4(0.f, 0.f, 0.f, 0.f);

  for (int kc = 0; kc < HID; kc += KC) {
    __syncthreads();
#pragma unroll
    for (int i = 0; i < 4; ++i) {
      int idx = tid + i * 256;
      ((float4*)sW)[idx] = ((const float4*)(W + (size_t)kc * HID))[idx];
    }
#pragma unroll
    for (int i = 0; i < 2; ++i) {
      int idx = tid + i * 256;
      int n = idx >> 3, kq = idx & 7;
      int node = base + n;
      float4 v = make_float4(0.f, 0.f, 0.f, 0.f);
      if (node < n_nodes) v = ((const float4*)(H + (size_t)node * HID + kc))[kq];
      ((float4*)sH)[idx] = v;
    }
    __syncthreads();
#pragma unroll
    for (int k = 0; k < KC; ++k) {
      float4 w = *(const float4*)&sW[k][cg * 4];
#pragma unroll
      for (int i = 0; i < 8; ++i) {
        float h = sH[ng + i * 8][k];
        acc[i].x += w.x * h; acc[i].y += w.y * h;
        acc[i].z += w.z * h; acc[i].w += w.w * h;
      }
    }
  }
#pragma unroll
  for (int i = 0; i < 8; ++i) {
    int node = base + ng + i * 8;
    if (node < n_nodes) ((float4*)(T + (size_t)node * HID))[cg] = acc[i];
  }
}

// ---------------- normalized aggregation + bias + relu ----------------
// one wave / dst node; lane owns 2 channels. Per 64-edge chunk: one coalesced
// csr load + one parallel dis gather, then readlane-broadcast and 8-deep MLP
// on the T-row gathers (kills the per-edge serial dependent chain).
__global__ __launch_bounds__(256) void aggregate_kernel(
    const float* __restrict__ T, const int* __restrict__ csr,
    const int* __restrict__ off, const int* __restrict__ deg,
    const float* __restrict__ dis, const float* __restrict__ bias,
    float* __restrict__ Hout) {
  int node = (blockIdx.x * blockDim.x + threadIdx.x) >> 6;
  int lane = threadIdx.x & 63;
  if (node >= N_NODES) return;
  const float2* __restrict__ T2 = (const float2*)T;
  float dd = dis[node];
  float2 b = ((const float2*)bias)[lane];
  float2 sv = T2[(size_t)node * 64 + lane];
  float wself = dd * dd;
  float ax = sv.x * wself, ay = sv.y * wself;
  int s0 = off[node], cnt = deg[node];
  for (int base = 0; base < cnt; base += 64) {
    int m = min(64, cnt - base);
    int sidx = 0; float wv = 0.f;
    if (lane < m) {
      sidx = csr[s0 + base + lane];   // coalesced vector load
      wv = dis[sidx] * dd;            // parallel gather
    }
    int j = 0;
    for (; j + 8 <= m; j += 8) {
#pragma unroll
      for (int q = 0; q < 8; ++q) {   // 8 independent row gathers in flight
        int s = __builtin_amdgcn_readlane(sidx, j + q);
        float w = __int_as_float(__builtin_amdgcn_readlane(__float_as_int(wv), j + q));
        float2 h = T2[(size_t)s * 64 + lane];
        ax += w * h.x; ay += w * h.y;
      }
    }
    for (; j < m; ++j) {
      int s = __builtin_amdgcn_readlane(sidx, j);
      float w = __int_as_float(__builtin_amdgcn_readlane(__float_as_int(wv), j));
      float2 h = T2[(size_t)s * 64 + lane];
      ax += w * h.x; ay += w * h.y;
    }
  }
  float2 o;
  o.x = fmaxf(ax + b.x, 0.f);
  o.y = fmaxf(ay + b.y, 0.f);
  ((float2*)Hout)[(size_t)node * 64 + lane] = o;
}

// ---------------- pooling: one block per graph (batch sorted -> contiguous) --
__global__ __launch_bounds__(256) void pool_kernel(
    const float* __restrict__ H, const int* __restrict__ start,
    float* __restrict__ pooled) {
  __shared__ float2 red[4][64];
  int g = blockIdx.x;
  int n0 = start[g], n1 = start[g + 1];
  int lane = threadIdx.x & 63, w = threadIdx.x >> 6;
  const float2* __restrict__ H2 = (const float2*)H;
  float ax = 0.f, ay = 0.f;
  for (int n = n0 + w; n < n1; n += 4) {
    float2 h = H2[(size_t)n * 64 + lane];
    ax += h.x; ay += h.y;
  }
  red[w][lane] = make_float2(ax, ay);
  __syncthreads();
  if (threadIdx.x < 64) {
    float2 a = red[0][lane], b1 = red[1][lane], c = red[2][lane], d = red[3][lane];
    float inv = 1.0f / fmaxf((float)(n1 - n0), 1.0f);
    float2 o;
    o.x = (a.x + b1.x + c.x + d.x) * inv;
    o.y = (a.y + b1.y + c.y + d.y) * inv;
    ((float2*)pooled)[g * 64 + lane] = o;
  }
}

// ---------------- FC head + log_softmax (1 wave / graph) ----------------
__global__ __launch_bounds__(64) void head_kernel(
    const float* __restrict__ pooled, const float* __restrict__ Wfc,
    const float* __restrict__ bfc, float* __restrict__ out) {
  int g = blockIdx.x;
  int lane = threadIdx.x;
  int o = lane & 15;
  float part = 0.f;
  for (int k = (lane >> 4); k < HID; k += 4)
    part += pooled[g * HID + k] * Wfc[k * OUT_C + o];
  part += __shfl_xor(part, 16);
  part += __shfl_xor(part, 32);
  float logit = part + bfc[o];
  float m = logit;
#pragma unroll
  for (int d = 8; d >= 1; d >>= 1) m = fmaxf(m, __shfl_xor(m, d, 16));
  float e = __expf(logit - m);
  float s = e;
#pragma unroll
  for (int d = 8; d >= 1; d >>= 1) s += __shfl_xor(s, d, 16);
  float r = logit - m - __logf(s);
  if (lane < 16) out[g * OUT_C + o] = r;
}

extern "C" void kernel_launch(void* const* d_in, const int* in_sizes, int n_in,
                              void* d_out, int out_size, void* d_ws, size_t ws_size,
                              hipStream_t stream) {
  const float* x    = (const float*)d_in[0];
  const int*   ei   = (const int*)d_in[1];
  const int*   batch= (const int*)d_in[2];
  const float* W1   = (const float*)d_in[3];
  const float* b1   = (const float*)d_in[4];
  const float* W2   = (const float*)d_in[5];
  const float* b2   = (const float*)d_in[6];
  const float* Wfc  = (const float*)d_in[7];
  const float* bfc  = (const float*)d_in[8];
  float* out = (float*)d_out;
  const int* src = ei;              // edge_index[0]
  const int* dst = ei + N_EDGES;    // edge_index[1]

  char* p = (char*)d_ws;
  auto alloc = [&](size_t bytes) { char* r = p; p += (bytes + 255) & ~255ull; return r; };
  int*   degI   = (int*)alloc((size_t)N_NODES * 4);
  float* dis    = (float*)alloc((size_t)N_NODES * 4);
  int*   off    = (int*)alloc((size_t)N_NODES * 4);
  int*   cursor = (int*)alloc((size_t)N_NODES * 4);
  int*   bsum   = (int*)alloc(256 * 4);
  int*   start  = (int*)alloc((N_GRAPHS + 1) * 4);
  float* pooled = (float*)alloc((size_t)N_GRAPHS * HID * 4);
  int*   csr    = (int*)alloc((size_t)N_EDGES * 4);
  float* T      = (float*)alloc((size_t)N_NODES * HID * 4);
  float* H      = (float*)alloc((size_t)N_NODES * HID * 4);

  hipMemsetAsync(degI,   0, (size_t)N_NODES * 4, stream);
  hipMemsetAsync(cursor, 0, (size_t)N_NODES * 4, stream);

  int nbN = (N_NODES + 255) / 256;
  int nbE = (N_EDGES + 255) / 256;

  deg_count_kernel<<<nbE, 256, 0, stream>>>(dst, degI);
  scan1_kernel<<<nbN, 256, 0, stream>>>(degI, off, bsum);
  scan2_bounds_kernel<<<1, 256, 0, stream>>>(bsum, nbN, batch, start);
  scan3_dis_kernel<<<nbN, 256, 0, stream>>>(off, bsum, degI, dis);
  fill_kernel<<<nbE, 256, 0, stream>>>(src, dst, off, cursor, csr);

  int gemm_blocks = (N_NODES + GN - 1) / GN;
  int agg_blocks  = (N_NODES * 64 + 255) / 256;

  gemm128_kernel<<<gemm_blocks, 256, 0, stream>>>(x, W1, T, N_NODES);
  aggregate_kernel<<<agg_blocks, 256, 0, stream>>>(T, csr, off, degI, dis, b1, H);
  gemm128_kernel<<<gemm_blocks, 256, 0, stream>>>(H, W2, T, N_NODES);
  aggregate_kernel<<<agg_blocks, 256, 0, stream>>>(T, csr, off, degI, dis, b2, H);

  pool_kernel<<<N_GRAPHS, 256, 0, stream>>>(H, start, pooled);
  head_kernel<<<N_GRAPHS, 64, 0, stream>>>(pooled, Wfc, bfc, out);
}

// Round 4
// 315.833 us; speedup vs baseline: 2.0598x; 1.2395x over previous
//
#include <hip/hip_runtime.h>

#define N_NODES  50000
#define N_EDGES  800000
#define HID      128
#define OUT_C    16
#define N_GRAPHS 128

typedef __attribute__((ext_vector_type(8))) short bf16x8;
typedef __attribute__((ext_vector_type(4))) float f32x4;
typedef __attribute__((ext_vector_type(8))) unsigned short us8;
typedef __attribute__((ext_vector_type(4))) unsigned short us4;

__device__ __forceinline__ unsigned short f2bf(float f) {
  unsigned u = __float_as_uint(f);
  u += 0x7fffu + ((u >> 16) & 1u);   // RNE
  return (unsigned short)(u >> 16);
}

// ---------------- degree ----------------
__global__ void deg_count_kernel(const int* __restrict__ dst, int* __restrict__ deg) {
  int e = blockIdx.x * blockDim.x + threadIdx.x;
  if (e < N_EDGES) atomicAdd(&deg[dst[e]], 1);
}

// ---------------- exclusive scan ----------------
__global__ void scan1_kernel(const int* __restrict__ deg, int* __restrict__ off,
                             int* __restrict__ bsum) {
  __shared__ int s[256];
  int i = blockIdx.x * 256 + threadIdx.x;
  int v = (i < N_NODES) ? deg[i] : 0;
  s[threadIdx.x] = v;
  __syncthreads();
  for (int d = 1; d < 256; d <<= 1) {
    int t = (threadIdx.x >= d) ? s[threadIdx.x - d] : 0;
    __syncthreads();
    s[threadIdx.x] += t;
    __syncthreads();
  }
  if (i < N_NODES) off[i] = s[threadIdx.x] - v;
  if (threadIdx.x == 255) bsum[blockIdx.x] = s[255];
}

__global__ void scan2_bounds_kernel(int* __restrict__ bsum, int nb,
                                    const int* __restrict__ batch,
                                    int* __restrict__ start) {
  __shared__ int s[256];
  int v = (threadIdx.x < nb) ? bsum[threadIdx.x] : 0;
  s[threadIdx.x] = v;
  __syncthreads();
  for (int d = 1; d < 256; d <<= 1) {
    int t = (threadIdx.x >= d) ? s[threadIdx.x - d] : 0;
    __syncthreads();
    s[threadIdx.x] += t;
    __syncthreads();
  }
  if (threadIdx.x < nb) bsum[threadIdx.x] = s[threadIdx.x] - v;
  int t = threadIdx.x;
  if (t <= N_GRAPHS) {
    int lo = 0, hi = N_NODES;
    while (lo < hi) {
      int mid = (lo + hi) >> 1;
      if (batch[mid] < t) lo = mid + 1; else hi = mid;
    }
    start[t] = lo;
  }
}

__global__ void scan3_dis_kernel(int* __restrict__ off, const int* __restrict__ bsum,
                                 const int* __restrict__ deg, float* __restrict__ dis) {
  int i = blockIdx.x * 256 + threadIdx.x;
  if (i < N_NODES) {
    off[i] += bsum[blockIdx.x];
    dis[i] = rsqrtf((float)deg[i] + 1.0f);
  }
}

// ---------------- CSR fill ----------------
__global__ void fill_kernel(const int* __restrict__ src, const int* __restrict__ dst,
                            const int* __restrict__ off, int* __restrict__ cursor,
                            int* __restrict__ csr) {
  int e = blockIdx.x * blockDim.x + threadIdx.x;
  if (e < N_EDGES) {
    int d = dst[e];
    int p = atomicAdd(&cursor[d], 1);
    csr[off[d] + p] = src[e];
  }
}

// ---------------- W transpose + bf16 convert (once) ----------------
__global__ void prep_wt_kernel(const float* __restrict__ W1, const float* __restrict__ W2,
                               unsigned short* __restrict__ wt1,
                               unsigned short* __restrict__ wt2) {
  int idx = blockIdx.x * 256 + threadIdx.x;  // 0..32767
  int sel = idx >> 14;
  int r = idx & 16383;
  int k = r >> 7, n = r & 127;
  const float* W = sel ? W2 : W1;
  unsigned short* wt = sel ? wt2 : wt1;
  wt[n * HID + k] = f2bf(W[k * HID + n]);   // wt[n][k] = W[k][n]
}

// ---------------- bf16 MFMA GEMM: T[n,:] = bf16( H[n,:] @ W ) ----------------
// 64 nodes/block, full 128 cols, K=128. 4 waves; wave w owns col-tiles {2w,2w+1}
// and all 4 node-tiles. 16x16x32 MFMA; A: m=lane&15,k=quad*8+j; B: n=lane&15,
// k=quad*8+j (from pre-transposed Wt); C/D: col=lane&15,row=quad*4+reg.
#define PAD 136   // +8 bf16 pad -> frag reads land 2-way (free) not 16-way
__global__ __launch_bounds__(256) void gemm_mfma_kernel(
    const float* __restrict__ H, const unsigned short* __restrict__ Wt,
    unsigned short* __restrict__ T, int n_nodes) {
  __shared__ unsigned short sA[64 * PAD];    // 17.4 KB (reused for output)
  __shared__ unsigned short sW[128 * PAD];   // 34.8 KB
  const int tid = threadIdx.x;
  const int lane = tid & 63;
  const int w = tid >> 6;
  const int l15 = lane & 15;
  const int quad = lane >> 4;
  const int base = blockIdx.x * 64;

  // stage Wt (coalesced us8): 128 rows x 16 chunks = 2048
#pragma unroll
  for (int i = 0; i < 8; ++i) {
    int idx = tid + i * 256;
    int row = idx >> 4;
    int col = (idx & 15) * 8;
    *(us8*)(sW + row * PAD + col) = *(const us8*)(Wt + row * HID + col);
  }
  // stage A: fp32 -> bf16: 64 rows x 32 float4 = 2048
#pragma unroll
  for (int i = 0; i < 8; ++i) {
    int idx = tid + i * 256;
    int nrow = idx >> 5;
    int c4 = (idx & 31) * 4;
    float4 v = make_float4(0.f, 0.f, 0.f, 0.f);
    int node = base + nrow;
    if (node < n_nodes) v = *(const float4*)(H + (size_t)node * HID + c4);
    us4 b;
    b.x = f2bf(v.x); b.y = f2bf(v.y); b.z = f2bf(v.z); b.w = f2bf(v.w);
    *(us4*)(sA + nrow * PAD + c4) = b;
  }
  __syncthreads();

  f32x4 acc[4][2];
#pragma unroll
  for (int nt = 0; nt < 4; ++nt)
#pragma unroll
    for (int c = 0; c < 2; ++c) acc[nt][c] = (f32x4)(0.f);

  const int ct0 = w * 2;
#pragma unroll
  for (int ks = 0; ks < 4; ++ks) {
    int koff = ks * 32 + quad * 8;
    bf16x8 a[4], bfr[2];
#pragma unroll
    for (int nt = 0; nt < 4; ++nt)
      a[nt] = *(const bf16x8*)(sA + (nt * 16 + l15) * PAD + koff);
#pragma unroll
    for (int c = 0; c < 2; ++c)
      bfr[c] = *(const bf16x8*)(sW + ((ct0 + c) * 16 + l15) * PAD + koff);
#pragma unroll
    for (int nt = 0; nt < 4; ++nt)
#pragma unroll
      for (int c = 0; c < 2; ++c)
        acc[nt][c] = __builtin_amdgcn_mfma_f32_16x16x32_bf16(a[nt], bfr[c], acc[nt][c], 0, 0, 0);
  }
  __syncthreads();

  // epilogue: acc -> bf16 in sA, then coalesced store
#pragma unroll
  for (int nt = 0; nt < 4; ++nt)
#pragma unroll
    for (int c = 0; c < 2; ++c)
#pragma unroll
      for (int r = 0; r < 4; ++r)
        sA[(nt * 16 + quad * 4 + r) * PAD + (ct0 + c) * 16 + l15] = f2bf(acc[nt][c][r]);
  __syncthreads();
  // 64 rows x 16 chunks = 1024 chunks -> 4 iterations (NOT 8: round-3 bug
  // wrote rows 64..127 from past-the-end LDS into other blocks' T rows)
#pragma unroll
  for (int i = 0; i < 4; ++i) {
    int idx = tid + i * 256;
    int nrow = idx >> 4;
    int col = (idx & 15) * 8;
    int node = base + nrow;
    if (node < n_nodes)
      *(us8*)(T + (size_t)node * HID + col) = *(const us8*)(sA + nrow * PAD + col);
  }
}

// ---------------- normalized aggregation + bias + relu (bf16 gather) --------
// one wave / dst node; lane owns 2 channels packed in one uint (2x bf16).
__global__ __launch_bounds__(256) void aggregate_kernel(
    const unsigned int* __restrict__ Tb, const int* __restrict__ csr,
    const int* __restrict__ off, const int* __restrict__ deg,
    const float* __restrict__ dis, const float* __restrict__ bias,
    float* __restrict__ Hout) {
  int node = (blockIdx.x * blockDim.x + threadIdx.x) >> 6;
  int lane = threadIdx.x & 63;
  if (node >= N_NODES) return;
  float dd = dis[node];
  float2 b = ((const float2*)bias)[lane];
  unsigned sv = Tb[(size_t)node * 64 + lane];
  float wself = dd * dd;
  float ax = __int_as_float(sv << 16) * wself;
  float ay = __int_as_float(sv & 0xffff0000u) * wself;
  int s0 = off[node], cnt = deg[node];
  for (int base = 0; base < cnt; base += 64) {
    int m = min(64, cnt - base);
    int sidx = 0; float wv = 0.f;
    if (lane < m) {
      sidx = csr[s0 + base + lane];   // coalesced
      wv = dis[sidx] * dd;            // parallel gather
    }
    int j = 0;
    for (; j + 8 <= m; j += 8) {
#pragma unroll
      for (int q = 0; q < 8; ++q) {   // 8 independent row gathers in flight
        int s = __builtin_amdgcn_readlane(sidx, j + q);
        float w = __int_as_float(__builtin_amdgcn_readlane(__float_as_int(wv), j + q));
        unsigned t = Tb[(size_t)s * 64 + lane];
        ax += w * __int_as_float(t << 16);
        ay += w * __int_as_float(t & 0xffff0000u);
      }
    }
    for (; j < m; ++j) {
      int s = __builtin_amdgcn_readlane(sidx, j);
      float w = __int_as_float(__builtin_amdgcn_readlane(__float_as_int(wv), j));
      unsigned t = Tb[(size_t)s * 64 + lane];
      ax += w * __int_as_float(t << 16);
      ay += w * __int_as_float(t & 0xffff0000u);
    }
  }
  float2 o;
  o.x = fmaxf(ax + b.x, 0.f);
  o.y = fmaxf(ay + b.y, 0.f);
  ((float2*)Hout)[(size_t)node * 64 + lane] = o;
}

// ---------------- pooling: one block per graph ----------------
__global__ __launch_bounds__(256) void pool_kernel(
    const float* __restrict__ H, const int* __restrict__ start,
    float* __restrict__ pooled) {
  __shared__ float2 red[4][64];
  int g = blockIdx.x;
  int n0 = start[g], n1 = start[g + 1];
  int lane = threadIdx.x & 63, w = threadIdx.x >> 6;
  const float2* __restrict__ H2 = (const float2*)H;
  float ax = 0.f, ay = 0.f;
  for (int n = n0 + w; n < n1; n += 4) {
    float2 h = H2[(size_t)n * 64 + lane];
    ax += h.x; ay += h.y;
  }
  red[w][lane] = make_float2(ax, ay);
  __syncthreads();
  if (threadIdx.x < 64) {
    float2 a = red[0][lane], b1 = red[1][lane], c = red[2][lane], d = red[3][lane];
    float inv = 1.0f / fmaxf((float)(n1 - n0), 1.0f);
    float2 o;
    o.x = (a.x + b1.x + c.x + d.x) * inv;
    o.y = (a.y + b1.y + c.y + d.y) * inv;
    ((float2*)pooled)[g * 64 + lane] = o;
  }
}

// ---------------- FC head + log_softmax (1 wave / graph) ----------------
__global__ __launch_bounds__(64) void head_kernel(
    const float* __restrict__ pooled, const float* __restrict__ Wfc,
    const float* __restrict__ bfc, float* __restrict__ out) {
  int g = blockIdx.x;
  int lane = threadIdx.x;
  int o = lane & 15;
  float part = 0.f;
  for (int k = (lane >> 4); k < HID; k += 4)
    part += pooled[g * HID + k] * Wfc[k * OUT_C + o];
  part += __shfl_xor(part, 16);
  part += __shfl_xor(part, 32);
  float logit = part + bfc[o];
  float m = logit;
#pragma unroll
  for (int d = 8; d >= 1; d >>= 1) m = fmaxf(m, __shfl_xor(m, d, 16));
  float e = __expf(logit - m);
  float s = e;
#pragma unroll
  for (int d = 8; d >= 1; d >>= 1) s += __shfl_xor(s, d, 16);
  float r = logit - m - __logf(s);
  if (lane < 16) out[g * OUT_C + o] = r;
}

extern "C" void kernel_launch(void* const* d_in, const int* in_sizes, int n_in,
                              void* d_out, int out_size, void* d_ws, size_t ws_size,
                              hipStream_t stream) {
  const float* x    = (const float*)d_in[0];
  const int*   ei   = (const int*)d_in[1];
  const int*   batch= (const int*)d_in[2];
  const float* W1   = (const float*)d_in[3];
  const float* b1   = (const float*)d_in[4];
  const float* W2   = (const float*)d_in[5];
  const float* b2   = (const float*)d_in[6];
  const float* Wfc  = (const float*)d_in[7];
  const float* bfc  = (const float*)d_in[8];
  float* out = (float*)d_out;
  const int* src = ei;              // edge_index[0]
  const int* dst = ei + N_EDGES;    // edge_index[1]

  char* p = (char*)d_ws;
  auto alloc = [&](size_t bytes) { char* r = p; p += (bytes + 255) & ~255ull; return r; };
  int*   degI   = (int*)alloc((size_t)N_NODES * 4);
  float* dis    = (float*)alloc((size_t)N_NODES * 4);
  int*   off    = (int*)alloc((size_t)N_NODES * 4);
  int*   cursor = (int*)alloc((size_t)N_NODES * 4);
  int*   bsum   = (int*)alloc(256 * 4);
  int*   start  = (int*)alloc((N_GRAPHS + 1) * 4);
  float* pooled = (float*)alloc((size_t)N_GRAPHS * HID * 4);
  int*   csr    = (int*)alloc((size_t)N_EDGES * 4);
  unsigned short* wt1 = (unsigned short*)alloc((size_t)HID * HID * 2);
  unsigned short* wt2 = (unsigned short*)alloc((size_t)HID * HID * 2);
  unsigned short* T   = (unsigned short*)alloc((size_t)N_NODES * HID * 2);
  float* H      = (float*)alloc((size_t)N_NODES * HID * 4);

  hipMemsetAsync(degI,   0, (size_t)N_NODES * 4, stream);
  hipMemsetAsync(cursor, 0, (size_t)N_NODES * 4, stream);

  int nbN = (N_NODES + 255) / 256;
  int nbE = (N_EDGES + 255) / 256;

  deg_count_kernel<<<nbE, 256, 0, stream>>>(dst, degI);
  scan1_kernel<<<nbN, 256, 0, stream>>>(degI, off, bsum);
  scan2_bounds_kernel<<<1, 256, 0, stream>>>(bsum, nbN, batch, start);
  scan3_dis_kernel<<<nbN, 256, 0, stream>>>(off, bsum, degI, dis);
  fill_kernel<<<nbE, 256, 0, stream>>>(src, dst, off, cursor, csr);
  prep_wt_kernel<<<128, 256, 0, stream>>>(W1, W2, wt1, wt2);

  int gemm_blocks = (N_NODES + 63) / 64;
  int agg_blocks  = (N_NODES * 64 + 255) / 256;

  gemm_mfma_kernel<<<gemm_blocks, 256, 0, stream>>>(x, wt1, T, N_NODES);
  aggregate_kernel<<<agg_blocks, 256, 0, stream>>>((const unsigned int*)T, csr, off, degI, dis, b1, H);
  gemm_mfma_kernel<<<gemm_blocks, 256, 0, stream>>>(H, wt2, T, N_NODES);
  aggregate_kernel<<<agg_blocks, 256, 0, stream>>>((const unsigned int*)T, csr, off, degI, dis, b2, H);

  pool_kernel<<<N_GRAPHS, 256, 0, stream>>>(H, start, pooled);
  head_kernel<<<N_GRAPHS, 64, 0, stream>>>(pooled, Wfc, bfc, out);
}

// Round 5
// 273.554 us; speedup vs baseline: 2.3781x; 1.1546x over previous
//
#include <hip/hip_runtime.h>

#define N_NODES  50000
#define N_EDGES  800000
#define HID      128
#define OUT_C    16
#define N_GRAPHS 128
#define MAXDEG   64   // Poisson(16): P(deg>=64) ~ 1e-19/node — safe bound, clamped anyway

typedef __attribute__((ext_vector_type(8))) short bf16x8;
typedef __attribute__((ext_vector_type(4))) float f32x4;
typedef __attribute__((ext_vector_type(8))) unsigned short us8;
typedef __attribute__((ext_vector_type(4))) unsigned short us4;

__device__ __forceinline__ unsigned short f2bf(float f) {
  unsigned u = __float_as_uint(f);
  u += 0x7fffu + ((u >> 16) & 1u);   // RNE
  return (unsigned short)(u >> 16);
}

// ---------------- fused degree-count + ELL fill ----------------
// slot = atomicAdd(deg[d]) doubles as both degree histogram and ELL cursor:
// kills the separate deg_count pass, the 3-kernel scan, and the off[] gather.
__global__ void fill_deg_kernel(const int* __restrict__ src, const int* __restrict__ dst,
                                int* __restrict__ deg, int* __restrict__ csr) {
  int e = blockIdx.x * blockDim.x + threadIdx.x;
  if (e < N_EDGES) {
    int d = dst[e];
    int p = atomicAdd(&deg[d], 1);
    if (p < MAXDEG) csr[(d << 6) + p] = src[e];
  }
}

// ---------------- graph segment bounds (batch is sorted) ----------------
__global__ void bounds_kernel(const int* __restrict__ batch, int* __restrict__ start) {
  int t = threadIdx.x;
  if (t <= N_GRAPHS) {
    int lo = 0, hi = N_NODES;
    while (lo < hi) {
      int mid = (lo + hi) >> 1;
      if (batch[mid] < t) lo = mid + 1; else hi = mid;
    }
    start[t] = lo;
  }
}

// ---------------- deg_inv_sqrt ----------------
__global__ void dis_kernel(const int* __restrict__ deg, float* __restrict__ dis) {
  int i = blockIdx.x * 256 + threadIdx.x;
  if (i < N_NODES) dis[i] = rsqrtf((float)deg[i] + 1.0f);  // +1 = self-loop
}

// ---------------- W transpose + bf16 convert (once) ----------------
__global__ void prep_wt_kernel(const float* __restrict__ W1, const float* __restrict__ W2,
                               unsigned short* __restrict__ wt1,
                               unsigned short* __restrict__ wt2) {
  int idx = blockIdx.x * 256 + threadIdx.x;  // 0..32767
  int sel = idx >> 14;
  int r = idx & 16383;
  int k = r >> 7, n = r & 127;
  const float* W = sel ? W2 : W1;
  unsigned short* wt = sel ? wt2 : wt1;
  wt[n * HID + k] = f2bf(W[k * HID + n]);   // wt[n][k] = W[k][n]
}

// ---------------- bf16 MFMA GEMM: T[n,:] = bf16( H[n,:] @ W ) ----------------
// 64 nodes/block, full 128 cols, K=128. 4 waves; wave w owns col-tiles {2w,2w+1}
// and all 4 node-tiles. 16x16x32 MFMA; A: m=lane&15,k=quad*8+j; B: n=lane&15,
// k=quad*8+j (from pre-transposed Wt); C/D: col=lane&15,row=quad*4+reg.
#define PAD 136   // +8 bf16 pad -> frag reads land 2-way (free) not 16-way
__global__ __launch_bounds__(256) void gemm_mfma_kernel(
    const float* __restrict__ H, const unsigned short* __restrict__ Wt,
    unsigned short* __restrict__ T, int n_nodes) {
  __shared__ unsigned short sA[64 * PAD];    // 17.4 KB (reused for output)
  __shared__ unsigned short sW[128 * PAD];   // 34.8 KB
  const int tid = threadIdx.x;
  const int lane = tid & 63;
  const int w = tid >> 6;
  const int l15 = lane & 15;
  const int quad = lane >> 4;
  const int base = blockIdx.x * 64;

  // stage Wt (coalesced us8): 128 rows x 16 chunks = 2048
#pragma unroll
  for (int i = 0; i < 8; ++i) {
    int idx = tid + i * 256;
    int row = idx >> 4;
    int col = (idx & 15) * 8;
    *(us8*)(sW + row * PAD + col) = *(const us8*)(Wt + row * HID + col);
  }
  // stage A: fp32 -> bf16: 64 rows x 32 float4 = 2048
#pragma unroll
  for (int i = 0; i < 8; ++i) {
    int idx = tid + i * 256;
    int nrow = idx >> 5;
    int c4 = (idx & 31) * 4;
    float4 v = make_float4(0.f, 0.f, 0.f, 0.f);
    int node = base + nrow;
    if (node < n_nodes) v = *(const float4*)(H + (size_t)node * HID + c4);
    us4 b;
    b.x = f2bf(v.x); b.y = f2bf(v.y); b.z = f2bf(v.z); b.w = f2bf(v.w);
    *(us4*)(sA + nrow * PAD + c4) = b;
  }
  __syncthreads();

  f32x4 acc[4][2];
#pragma unroll
  for (int nt = 0; nt < 4; ++nt)
#pragma unroll
    for (int c = 0; c < 2; ++c) acc[nt][c] = (f32x4)(0.f);

  const int ct0 = w * 2;
#pragma unroll
  for (int ks = 0; ks < 4; ++ks) {
    int koff = ks * 32 + quad * 8;
    bf16x8 a[4], bfr[2];
#pragma unroll
    for (int nt = 0; nt < 4; ++nt)
      a[nt] = *(const bf16x8*)(sA + (nt * 16 + l15) * PAD + koff);
#pragma unroll
    for (int c = 0; c < 2; ++c)
      bfr[c] = *(const bf16x8*)(sW + ((ct0 + c) * 16 + l15) * PAD + koff);
#pragma unroll
    for (int nt = 0; nt < 4; ++nt)
#pragma unroll
      for (int c = 0; c < 2; ++c)
        acc[nt][c] = __builtin_amdgcn_mfma_f32_16x16x32_bf16(a[nt], bfr[c], acc[nt][c], 0, 0, 0);
  }
  __syncthreads();

  // epilogue: acc -> bf16 in sA, then coalesced store (64 rows -> 4 iters)
#pragma unroll
  for (int nt = 0; nt < 4; ++nt)
#pragma unroll
    for (int c = 0; c < 2; ++c)
#pragma unroll
      for (int r = 0; r < 4; ++r)
        sA[(nt * 16 + quad * 4 + r) * PAD + (ct0 + c) * 16 + l15] = f2bf(acc[nt][c][r]);
  __syncthreads();
#pragma unroll
  for (int i = 0; i < 4; ++i) {
    int idx = tid + i * 256;
    int nrow = idx >> 4;
    int col = (idx & 15) * 8;
    int node = base + nrow;
    if (node < n_nodes)
      *(us8*)(T + (size_t)node * HID + col) = *(const us8*)(sA + nrow * PAD + col);
  }
}

// ---------------- normalized aggregation + bias + relu (bf16 ELL gather) ----
// one wave / dst node; lane owns 2 channels packed in one uint (2x bf16).
__global__ __launch_bounds__(256) void aggregate_kernel(
    const unsigned int* __restrict__ Tb, const int* __restrict__ csr,
    const int* __restrict__ deg, const float* __restrict__ dis,
    const float* __restrict__ bias, float* __restrict__ Hout) {
  int node = (blockIdx.x * blockDim.x + threadIdx.x) >> 6;
  int lane = threadIdx.x & 63;
  if (node >= N_NODES) return;
  float dd = dis[node];
  float2 b = ((const float2*)bias)[lane];
  unsigned sv = Tb[(size_t)node * 64 + lane];
  float wself = dd * dd;
  float ax = __int_as_float(sv << 16) * wself;
  float ay = __int_as_float(sv & 0xffff0000u) * wself;
  int cnt = min(deg[node], MAXDEG);
  int s0 = node << 6;
  {
    int m = cnt;
    int sidx = 0; float wv = 0.f;
    if (lane < m) {
      sidx = csr[s0 + lane];          // coalesced (ELL row contiguous)
      wv = dis[sidx] * dd;            // parallel gather
    }
    int j = 0;
    for (; j + 8 <= m; j += 8) {
#pragma unroll
      for (int q = 0; q < 8; ++q) {   // 8 independent row gathers in flight
        int s = __builtin_amdgcn_readlane(sidx, j + q);
        float w = __int_as_float(__builtin_amdgcn_readlane(__float_as_int(wv), j + q));
        unsigned t = Tb[(size_t)s * 64 + lane];
        ax += w * __int_as_float(t << 16);
        ay += w * __int_as_float(t & 0xffff0000u);
      }
    }
    for (; j < m; ++j) {
      int s = __builtin_amdgcn_readlane(sidx, j);
      float w = __int_as_float(__builtin_amdgcn_readlane(__float_as_int(wv), j));
      unsigned t = Tb[(size_t)s * 64 + lane];
      ax += w * __int_as_float(t << 16);
      ay += w * __int_as_float(t & 0xffff0000u);
    }
  }
  float2 o;
  o.x = fmaxf(ax + b.x, 0.f);
  o.y = fmaxf(ay + b.y, 0.f);
  ((float2*)Hout)[(size_t)node * 64 + lane] = o;
}

// ---------------- pooling: one block per graph ----------------
__global__ __launch_bounds__(256) void pool_kernel(
    const float* __restrict__ H, const int* __restrict__ start,
    float* __restrict__ pooled) {
  __shared__ float2 red[4][64];
  int g = blockIdx.x;
  int n0 = start[g], n1 = start[g + 1];
  int lane = threadIdx.x & 63, w = threadIdx.x >> 6;
  const float2* __restrict__ H2 = (const float2*)H;
  float ax = 0.f, ay = 0.f;
  for (int n = n0 + w; n < n1; n += 4) {
    float2 h = H2[(size_t)n * 64 + lane];
    ax += h.x; ay += h.y;
  }
  red[w][lane] = make_float2(ax, ay);
  __syncthreads();
  if (threadIdx.x < 64) {
    float2 a = red[0][lane], b1 = red[1][lane], c = red[2][lane], d = red[3][lane];
    float inv = 1.0f / fmaxf((float)(n1 - n0), 1.0f);
    float2 o;
    o.x = (a.x + b1.x + c.x + d.x) * inv;
    o.y = (a.y + b1.y + c.y + d.y) * inv;
    ((float2*)pooled)[g * 64 + lane] = o;
  }
}

// ---------------- FC head + log_softmax (1 wave / graph) ----------------
__global__ __launch_bounds__(64) void head_kernel(
    const float* __restrict__ pooled, const float* __restrict__ Wfc,
    const float* __restrict__ bfc, float* __restrict__ out) {
  int g = blockIdx.x;
  int lane = threadIdx.x;
  int o = lane & 15;
  float part = 0.f;
  for (int k = (lane >> 4); k < HID; k += 4)
    part += pooled[g * HID + k] * Wfc[k * OUT_C + o];
  part += __shfl_xor(part, 16);
  part += __shfl_xor(part, 32);
  float logit = part + bfc[o];
  float m = logit;
#pragma unroll
  for (int d = 8; d >= 1; d >>= 1) m = fmaxf(m, __shfl_xor(m, d, 16));
  float e = __expf(logit - m);
  float s = e;
#pragma unroll
  for (int d = 8; d >= 1; d >>= 1) s += __shfl_xor(s, d, 16);
  float r = logit - m - __logf(s);
  if (lane < 16) out[g * OUT_C + o] = r;
}

extern "C" void kernel_launch(void* const* d_in, const int* in_sizes, int n_in,
                              void* d_out, int out_size, void* d_ws, size_t ws_size,
                              hipStream_t stream) {
  const float* x    = (const float*)d_in[0];
  const int*   ei   = (const int*)d_in[1];
  const int*   batch= (const int*)d_in[2];
  const float* W1   = (const float*)d_in[3];
  const float* b1   = (const float*)d_in[4];
  const float* W2   = (const float*)d_in[5];
  const float* b2   = (const float*)d_in[6];
  const float* Wfc  = (const float*)d_in[7];
  const float* bfc  = (const float*)d_in[8];
  float* out = (float*)d_out;
  const int* src = ei;              // edge_index[0]
  const int* dst = ei + N_EDGES;    // edge_index[1]

  char* p = (char*)d_ws;
  auto alloc = [&](size_t bytes) { char* r = p; p += (bytes + 255) & ~255ull; return r; };
  int*   degI   = (int*)alloc((size_t)N_NODES * 4);
  float* dis    = (float*)alloc((size_t)N_NODES * 4);
  int*   start  = (int*)alloc((N_GRAPHS + 1) * 4);
  float* pooled = (float*)alloc((size_t)N_GRAPHS * HID * 4);
  int*   csr    = (int*)alloc((size_t)N_NODES * MAXDEG * 4);   // ELL, 12.8 MB
  unsigned short* wt1 = (unsigned short*)alloc((size_t)HID * HID * 2);
  unsigned short* wt2 = (unsigned short*)alloc((size_t)HID * HID * 2);
  unsigned short* T   = (unsigned short*)alloc((size_t)N_NODES * HID * 2);
  float* H      = (float*)alloc((size_t)N_NODES * HID * 4);

  hipMemsetAsync(degI, 0, (size_t)N_NODES * 4, stream);

  int nbN = (N_NODES + 255) / 256;
  int nbE = (N_EDGES + 255) / 256;

  fill_deg_kernel<<<nbE, 256, 0, stream>>>(src, dst, degI, csr);
  bounds_kernel<<<1, 256, 0, stream>>>(batch, start);
  dis_kernel<<<nbN, 256, 0, stream>>>(degI, dis);
  prep_wt_kernel<<<128, 256, 0, stream>>>(W1, W2, wt1, wt2);

  int gemm_blocks = (N_NODES + 63) / 64;
  int agg_blocks  = (N_NODES * 64 + 255) / 256;

  gemm_mfma_kernel<<<gemm_blocks, 256, 0, stream>>>(x, wt1, T, N_NODES);
  aggregate_kernel<<<agg_blocks, 256, 0, stream>>>((const unsigned int*)T, csr, degI, dis, b1, H);
  gemm_mfma_kernel<<<gemm_blocks, 256, 0, stream>>>(H, wt2, T, N_NODES);
  aggregate_kernel<<<agg_blocks, 256, 0, stream>>>((const unsigned int*)T, csr, degI, dis, b2, H);

  pool_kernel<<<N_GRAPHS, 256, 0, stream>>>(H, start, pooled);
  head_kernel<<<N_GRAPHS, 64, 0, stream>>>(pooled, Wfc, bfc, out);
}

// Round 6
// 262.518 us; speedup vs baseline: 2.4781x; 1.0420x over previous
//
#include <hip/hip_runtime.h>

#define N_NODES  50000
#define N_EDGES  800000
#define HID      128
#define OUT_C    16
#define N_GRAPHS 128
#define MAXDEG   64     // Poisson(16): P(deg>=64) ~ 1e-19/node — clamped anyway
#define NSLICE   6250   // N_NODES / 8 exactly; slice s owns [s*6250, (s+1)*6250)
#define EPB      8192   // edges per chunk

typedef __attribute__((ext_vector_type(8))) short bf16x8;
typedef __attribute__((ext_vector_type(4))) float f32x4;
typedef __attribute__((ext_vector_type(8))) unsigned short us8;
typedef __attribute__((ext_vector_type(4))) unsigned short us4;

__device__ __forceinline__ unsigned short f2bf(float f) {
  unsigned u = __float_as_uint(f);
  u += 0x7fffu + ((u >> 16) & 1u);   // RNE
  return (unsigned short)(u >> 16);
}

// ---------------- XCD-sharded degree-count + ELL fill ----------------
// block b: edge chunk b>>3, node slice b&7. blockIdx%8 -> XCD round-robin, so
// every writer of a given deg/ell line is on ONE XCD: dirty lines are written
// back once (round-5 counter: WRITE_SIZE = 800k x 64B = full-line write-back
// per scattered store from 8 XCDs). 8x edge re-read is L3-absorbed.
__global__ __launch_bounds__(256) void fill_deg_kernel(
    const int* __restrict__ src, const int* __restrict__ dst,
    int* __restrict__ deg, unsigned short* __restrict__ ell) {
  const int slice = blockIdx.x & 7;
  const int e0 = (blockIdx.x >> 3) * EPB;
  const int e1 = min(e0 + EPB, N_EDGES);
  const unsigned lo = slice * NSLICE;
  for (int e = e0 + threadIdx.x; e < e1; e += 256) {
    int d = dst[e];
    if ((unsigned)(d - lo) < (unsigned)NSLICE) {
      int p = atomicAdd(&deg[d], 1);
      if (p < MAXDEG) ell[(d << 6) + p] = (unsigned short)src[e];
    }
  }
}

// ---------------- fused prep: Wt transpose+bf16 | deg_inv_sqrt | bounds -----
__global__ void prep_kernel(const float* __restrict__ W1, const float* __restrict__ W2,
                            unsigned short* __restrict__ wt1, unsigned short* __restrict__ wt2,
                            const int* __restrict__ deg, float* __restrict__ dis,
                            const int* __restrict__ batch, int* __restrict__ start) {
  int b = blockIdx.x;
  if (b < 128) {                       // W transpose: 2*16384 elems
    int idx = b * 256 + threadIdx.x;
    int sel = idx >> 14;
    int r = idx & 16383;
    int k = r >> 7, n = r & 127;
    const float* W = sel ? W2 : W1;
    unsigned short* wt = sel ? wt2 : wt1;
    wt[n * HID + k] = f2bf(W[k * HID + n]);   // wt[n][k] = W[k][n]
  } else if (b < 324) {                // deg_inv_sqrt over 50000 nodes
    int i = (b - 128) * 256 + threadIdx.x;
    if (i < N_NODES) dis[i] = rsqrtf((float)deg[i] + 1.0f);  // +1 self-loop
  } else {                             // graph bounds (batch sorted)
    int t = threadIdx.x;
    if (t <= N_GRAPHS) {
      int lo = 0, hi = N_NODES;
      while (lo < hi) {
        int mid = (lo + hi) >> 1;
        if (batch[mid] < t) lo = mid + 1; else hi = mid;
      }
      start[t] = lo;
    }
  }
}

// ---------------- bf16 MFMA GEMM: T[n,:] = bf16( H[n,:] @ W ) ----------------
// 64 nodes/block, full 128 cols, K=128. 4 waves; wave w owns col-tiles {2w,2w+1}
// and all 4 node-tiles. 16x16x32 MFMA; A: m=lane&15,k=quad*8+j; B: n=lane&15,
// k=quad*8+j (from pre-transposed Wt); C/D: col=lane&15,row=quad*4+reg.
#define PAD 136   // +8 bf16 pad -> frag reads land 2-way (free) not 16-way
__global__ __launch_bounds__(256) void gemm_mfma_kernel(
    const float* __restrict__ H, const unsigned short* __restrict__ Wt,
    unsigned short* __restrict__ T, int n_nodes) {
  __shared__ unsigned short sA[64 * PAD];    // 17.4 KB (reused for output)
  __shared__ unsigned short sW[128 * PAD];   // 34.8 KB
  const int tid = threadIdx.x;
  const int lane = tid & 63;
  const int w = tid >> 6;
  const int l15 = lane & 15;
  const int quad = lane >> 4;
  const int base = blockIdx.x * 64;

  // stage Wt (coalesced us8): 128 rows x 16 chunks = 2048
#pragma unroll
  for (int i = 0; i < 8; ++i) {
    int idx = tid + i * 256;
    int row = idx >> 4;
    int col = (idx & 15) * 8;
    *(us8*)(sW + row * PAD + col) = *(const us8*)(Wt + row * HID + col);
  }
  // stage A: fp32 -> bf16: 64 rows x 32 float4 = 2048
#pragma unroll
  for (int i = 0; i < 8; ++i) {
    int idx = tid + i * 256;
    int nrow = idx >> 5;
    int c4 = (idx & 31) * 4;
    float4 v = make_float4(0.f, 0.f, 0.f, 0.f);
    int node = base + nrow;
    if (node < n_nodes) v = *(const float4*)(H + (size_t)node * HID + c4);
    us4 b;
    b.x = f2bf(v.x); b.y = f2bf(v.y); b.z = f2bf(v.z); b.w = f2bf(v.w);
    *(us4*)(sA + nrow * PAD + c4) = b;
  }
  __syncthreads();

  f32x4 acc[4][2];
#pragma unroll
  for (int nt = 0; nt < 4; ++nt)
#pragma unroll
    for (int c = 0; c < 2; ++c) acc[nt][c] = (f32x4)(0.f);

  const int ct0 = w * 2;
#pragma unroll
  for (int ks = 0; ks < 4; ++ks) {
    int koff = ks * 32 + quad * 8;
    bf16x8 a[4], bfr[2];
#pragma unroll
    for (int nt = 0; nt < 4; ++nt)
      a[nt] = *(const bf16x8*)(sA + (nt * 16 + l15) * PAD + koff);
#pragma unroll
    for (int c = 0; c < 2; ++c)
      bfr[c] = *(const bf16x8*)(sW + ((ct0 + c) * 16 + l15) * PAD + koff);
#pragma unroll
    for (int nt = 0; nt < 4; ++nt)
#pragma unroll
      for (int c = 0; c < 2; ++c)
        acc[nt][c] = __builtin_amdgcn_mfma_f32_16x16x32_bf16(a[nt], bfr[c], acc[nt][c], 0, 0, 0);
  }
  __syncthreads();

  // epilogue: acc -> bf16 in sA, then coalesced store (64 rows -> 4 iters)
#pragma unroll
  for (int nt = 0; nt < 4; ++nt)
#pragma unroll
    for (int c = 0; c < 2; ++c)
#pragma unroll
      for (int r = 0; r < 4; ++r)
        sA[(nt * 16 + quad * 4 + r) * PAD + (ct0 + c) * 16 + l15] = f2bf(acc[nt][c][r]);
  __syncthreads();
#pragma unroll
  for (int i = 0; i < 4; ++i) {
    int idx = tid + i * 256;
    int nrow = idx >> 4;
    int col = (idx & 15) * 8;
    int node = base + nrow;
    if (node < n_nodes)
      *(us8*)(T + (size_t)node * HID + col) = *(const us8*)(sA + nrow * PAD + col);
  }
}

// ---------------- normalized aggregation + bias + relu (bf16 ELL gather) ----
// one wave / dst node; lane owns 2 channels packed in one uint (2x bf16).
__global__ __launch_bounds__(256) void aggregate_kernel(
    const unsigned int* __restrict__ Tb, const unsigned short* __restrict__ ell,
    const int* __restrict__ deg, const float* __restrict__ dis,
    const float* __restrict__ bias, float* __restrict__ Hout) {
  int node = (blockIdx.x * blockDim.x + threadIdx.x) >> 6;
  int lane = threadIdx.x & 63;
  if (node >= N_NODES) return;
  float dd = dis[node];
  float2 b = ((const float2*)bias)[lane];
  unsigned sv = Tb[(size_t)node * 64 + lane];
  float wself = dd * dd;
  float ax = __int_as_float(sv << 16) * wself;
  float ay = __int_as_float(sv & 0xffff0000u) * wself;
  int m = min(deg[node], MAXDEG);
  int s0 = node << 6;
  int sidx = 0; float wv = 0.f;
  if (lane < m) {
    sidx = (int)ell[s0 + lane];       // coalesced (ELL row contiguous)
    wv = dis[sidx] * dd;              // parallel gather
  }
  int j = 0;
  for (; j + 8 <= m; j += 8) {
#pragma unroll
    for (int q = 0; q < 8; ++q) {     // 8 independent row gathers in flight
      int s = __builtin_amdgcn_readlane(sidx, j + q);
      float w = __int_as_float(__builtin_amdgcn_readlane(__float_as_int(wv), j + q));
      unsigned t = Tb[(size_t)s * 64 + lane];
      ax += w * __int_as_float(t << 16);
      ay += w * __int_as_float(t & 0xffff0000u);
    }
  }
  for (; j < m; ++j) {
    int s = __builtin_amdgcn_readlane(sidx, j);
    float w = __int_as_float(__builtin_amdgcn_readlane(__float_as_int(wv), j));
    unsigned t = Tb[(size_t)s * 64 + lane];
    ax += w * __int_as_float(t << 16);
    ay += w * __int_as_float(t & 0xffff0000u);
  }
  float2 o;
  o.x = fmaxf(ax + b.x, 0.f);
  o.y = fmaxf(ay + b.y, 0.f);
  ((float2*)Hout)[(size_t)node * 64 + lane] = o;
}

// ---------------- pooling: one block per graph ----------------
__global__ __launch_bounds__(256) void pool_kernel(
    const float* __restrict__ H, const int* __restrict__ start,
    float* __restrict__ pooled) {
  __shared__ float2 red[4][64];
  int g = blockIdx.x;
  int n0 = start[g], n1 = start[g + 1];
  int lane = threadIdx.x & 63, w = threadIdx.x >> 6;
  const float2* __restrict__ H2 = (const float2*)H;
  float ax = 0.f, ay = 0.f;
  for (int n = n0 + w; n < n1; n += 4) {
    float2 h = H2[(size_t)n * 64 + lane];
    ax += h.x; ay += h.y;
  }
  red[w][lane] = make_float2(ax, ay);
  __syncthreads();
  if (threadIdx.x < 64) {
    float2 a = red[0][lane], b1 = red[1][lane], c = red[2][lane], d = red[3][lane];
    float inv = 1.0f / fmaxf((float)(n1 - n0), 1.0f);
    float2 o;
    o.x = (a.x + b1.x + c.x + d.x) * inv;
    o.y = (a.y + b1.y + c.y + d.y) * inv;
    ((float2*)pooled)[g * 64 + lane] = o;
  }
}

// ---------------- FC head + log_softmax (1 wave / graph) ----------------
__global__ __launch_bounds__(64) void head_kernel(
    const float* __restrict__ pooled, const float* __restrict__ Wfc,
    const float* __restrict__ bfc, float* __restrict__ out) {
  int g = blockIdx.x;
  int lane = threadIdx.x;
  int o = lane & 15;
  float part = 0.f;
  for (int k = (lane >> 4); k < HID; k += 4)
    part += pooled[g * HID + k] * Wfc[k * OUT_C + o];
  part += __shfl_xor(part, 16);
  part += __shfl_xor(part, 32);
  float logit = part + bfc[o];
  float m = logit;
#pragma unroll
  for (int d = 8; d >= 1; d >>= 1) m = fmaxf(m, __shfl_xor(m, d, 16));
  float e = __expf(logit - m);
  float s = e;
#pragma unroll
  for (int d = 8; d >= 1; d >>= 1) s += __shfl_xor(s, d, 16);
  float r = logit - m - __logf(s);
  if (lane < 16) out[g * OUT_C + o] = r;
}

extern "C" void kernel_launch(void* const* d_in, const int* in_sizes, int n_in,
                              void* d_out, int out_size, void* d_ws, size_t ws_size,
                              hipStream_t stream) {
  const float* x    = (const float*)d_in[0];
  const int*   ei   = (const int*)d_in[1];
  const int*   batch= (const int*)d_in[2];
  const float* W1   = (const float*)d_in[3];
  const float* b1   = (const float*)d_in[4];
  const float* W2   = (const float*)d_in[5];
  const float* b2   = (const float*)d_in[6];
  const float* Wfc  = (const float*)d_in[7];
  const float* bfc  = (const float*)d_in[8];
  float* out = (float*)d_out;
  const int* src = ei;              // edge_index[0]
  const int* dst = ei + N_EDGES;    // edge_index[1]

  char* p = (char*)d_ws;
  auto alloc = [&](size_t bytes) { char* r = p; p += (bytes + 255) & ~255ull; return r; };
  int*   degI   = (int*)alloc((size_t)N_NODES * 4);
  float* dis    = (float*)alloc((size_t)N_NODES * 4);
  int*   start  = (int*)alloc((N_GRAPHS + 1) * 4);
  float* pooled = (float*)alloc((size_t)N_GRAPHS * HID * 4);
  unsigned short* ell = (unsigned short*)alloc((size_t)N_NODES * MAXDEG * 2); // 6.4 MB
  unsigned short* wt1 = (unsigned short*)alloc((size_t)HID * HID * 2);
  unsigned short* wt2 = (unsigned short*)alloc((size_t)HID * HID * 2);
  unsigned short* T   = (unsigned short*)alloc((size_t)N_NODES * HID * 2);
  float* H      = (float*)alloc((size_t)N_NODES * HID * 4);

  hipMemsetAsync(degI, 0, (size_t)N_NODES * 4, stream);

  int fill_blocks = ((N_EDGES + EPB - 1) / EPB) * 8;   // 98 chunks x 8 slices

  fill_deg_kernel<<<fill_blocks, 256, 0, stream>>>(src, dst, degI, ell);
  prep_kernel<<<325, 256, 0, stream>>>(W1, W2, wt1, wt2, degI, dis, batch, start);

  int gemm_blocks = (N_NODES + 63) / 64;
  int agg_blocks  = (N_NODES * 64 + 255) / 256;

  gemm_mfma_kernel<<<gemm_blocks, 256, 0, stream>>>(x, wt1, T, N_NODES);
  aggregate_kernel<<<agg_blocks, 256, 0, stream>>>((const unsigned int*)T, ell, degI, dis, b1, H);
  gemm_mfma_kernel<<<gemm_blocks, 256, 0, stream>>>(H, wt2, T, N_NODES);
  aggregate_kernel<<<agg_blocks, 256, 0, stream>>>((const unsigned int*)T, ell, degI, dis, b2, H);

  pool_kernel<<<N_GRAPHS, 256, 0, stream>>>(H, start, pooled);
  head_kernel<<<N_GRAPHS, 64, 0, stream>>>(pooled, Wfc, bfc, out);
}